// Round 12
// baseline (3833.921 us; speedup 1.0000x reference)
//
#include <hip/hip_runtime.h>
#include <hip/hip_bf16.h>
#include <stdint.h>

#define SEQ   512
#define BATCH 1024
#define IN_F  256
#define HID   512
#define OUT_F 64

typedef float f32x2 __attribute__((ext_vector_type(2)));

// ws layout (bytes)
static const size_t OFF_V   = 0;          // 1024*512*4 = 2 MB
static const size_t OFF_I   = 2097152;    // 2 MB
static const size_t OFF_VO  = 4194304;    // 256 KB
static const size_t OFF_IO  = 4456448;    // 256 KB
static const size_t OFF_ZM  = 4718592;    // 64 KB
static const size_t OFF_WRT = 4784128;    // pw: 513*256*8 = 1050624 (row 512 zeros)
static const size_t OFF_WOT = 5834752;    // 513*64*4 = 131328 (fp32, row 512 zeros)
static const size_t OFF_CUR = 5966080;    // 2 ping-pong cur buffers, CHUNK*2MB each

__global__ void init_state_kernel(float4* __restrict__ p, int n4) {
    int i = blockIdx.x * blockDim.x + threadIdx.x;
    int stride = gridDim.x * blockDim.x;
    float4 z = make_float4(0.f, 0.f, 0.f, 0.f);
    for (; i < n4; i += stride) p[i] = z;
}

// pw[j][h2] = (w_rec[h2][j], w_rec[h2+256][j]) : one float2 load feeds h2 and h2+256.
__global__ void prep_kernel(const float* __restrict__ wrec, const float* __restrict__ wout,
                            float2* __restrict__ pw, float* __restrict__ woutT) {
    int i = blockIdx.x * blockDim.x + threadIdx.x;
    int stride = gridDim.x * blockDim.x;
    for (int idx = i; idx < 513 * 256; idx += stride) {
        int j = idx >> 8, h2 = idx & 255;
        float2 v = make_float2(0.f, 0.f);
        if (j < 512) {
            v.x = wrec[h2 * 512 + j];
            v.y = wrec[(h2 + 256) * 512 + j];
        }
        pw[idx] = v;
    }
    for (int idx = i; idx < 513 * 64; idx += stride) {
        int h = idx >> 6, o = idx & 63;
        woutT[idx] = (h < 512) ? wout[o * 512 + h] : 0.0f;   // woutT[h][o] = w_out[o][h]
    }
}

// ===== Standalone prologue GEMM (VERBATIM R10; NUMERICS LOCKED: each C[m][n]
// is ONE fma chain over k=0..255 ascending). Full occupancy, 128x128 tile. =====
#define GBM 128
#define GBN 128
#define GBK 16
#define GLDK 132

__launch_bounds__(256)
__global__ void gemm_kernel(const float* __restrict__ A, const float* __restrict__ Bw,
                            float* __restrict__ C) {
    __shared__ float As[2][GBK][GLDK];
    __shared__ float Bs[2][GBK][GLDK];

    const int nwg = gridDim.x;
    const int cpx = nwg >> 3;
    const int logical = ((int)blockIdx.x & 7) * cpx + ((int)blockIdx.x >> 3);
    const int mb = logical >> 2;
    const int nb = logical & 3;

    const int t = threadIdx.x;
    const size_t m0 = (size_t)mb * GBM;
    const int n0 = nb * GBN;

    const int r  = t >> 1;
    const int kh = (t & 1) << 3;
    const float* Ap = A  + (m0 + (size_t)r) * IN_F + kh;
    const float* Bp = Bw + (size_t)(n0 + r) * IN_F + kh;

    const int wv   = t >> 6;
    const int lane = t & 63;
    const int tm = ((wv >> 1) << 3) | (lane >> 3);
    const int tn = ((wv & 1) << 3) | (lane & 7);

    f32x2 acc[8][4] = {};

    {
        float4 a0 = *(const float4*)(Ap + 0);
        float4 a1 = *(const float4*)(Ap + 4);
        float4 b0 = *(const float4*)(Bp + 0);
        float4 b1 = *(const float4*)(Bp + 4);
        float av[8], bv[8];
        *(float4*)(av + 0) = a0; *(float4*)(av + 4) = a1;
        *(float4*)(bv + 0) = b0; *(float4*)(bv + 4) = b1;
        #pragma unroll
        for (int i = 0; i < 8; ++i) {
            As[0][kh + i][r] = av[i];
            Bs[0][kh + i][r] = bv[i];
        }
    }

    int c = 0;
    for (int k0 = 0; k0 < IN_F; k0 += GBK) {
        __syncthreads();
        float4 a0, a1, b0, b1;
        const bool more = (k0 + GBK) < IN_F;
        if (more) {
            const int kn = k0 + GBK;
            a0 = *(const float4*)(Ap + kn);
            a1 = *(const float4*)(Ap + kn + 4);
            b0 = *(const float4*)(Bp + kn);
            b1 = *(const float4*)(Bp + kn + 4);
        }
        #pragma unroll
        for (int k = 0; k < GBK; ++k) {
            float am[8], bn[8];
            *(float4*)(am + 0) = *(const float4*)&As[c][k][tm * 8];
            *(float4*)(am + 4) = *(const float4*)&As[c][k][tm * 8 + 4];
            *(float4*)(bn + 0) = *(const float4*)&Bs[c][k][tn * 8];
            *(float4*)(bn + 4) = *(const float4*)&Bs[c][k][tn * 8 + 4];
            f32x2 bp0 = { bn[0], bn[1] }, bp1 = { bn[2], bn[3] };
            f32x2 bp2 = { bn[4], bn[5] }, bp3 = { bn[6], bn[7] };
            #pragma unroll
            for (int rr = 0; rr < 8; ++rr) {
                f32x2 ar = { am[rr], am[rr] };
                acc[rr][0] = __builtin_elementwise_fma(ar, bp0, acc[rr][0]);
                acc[rr][1] = __builtin_elementwise_fma(ar, bp1, acc[rr][1]);
                acc[rr][2] = __builtin_elementwise_fma(ar, bp2, acc[rr][2]);
                acc[rr][3] = __builtin_elementwise_fma(ar, bp3, acc[rr][3]);
            }
        }
        if (more) {
            float av[8], bv[8];
            *(float4*)(av + 0) = a0; *(float4*)(av + 4) = a1;
            *(float4*)(bv + 0) = b0; *(float4*)(bv + 4) = b1;
            #pragma unroll
            for (int i = 0; i < 8; ++i) {
                As[c ^ 1][kh + i][r] = av[i];
                Bs[c ^ 1][kh + i][r] = bv[i];
            }
        }
        c ^= 1;
    }
    #pragma unroll
    for (int rr = 0; rr < 8; ++rr) {
        float* Cp = C + (m0 + (size_t)(tm * 8 + rr)) * HID + n0 + tn * 8;
        float4 c0 = make_float4(acc[rr][0][0], acc[rr][0][1], acc[rr][1][0], acc[rr][1][1]);
        float4 c1 = make_float4(acc[rr][2][0], acc[rr][2][1], acc[rr][3][0], acc[rr][3][1]);
        *(float4*)(Cp + 0) = c0;
        *(float4*)(Cp + 4) = c1;
    }
}

// ===== FAT kernel: blocks 0..1023 = R8-form 256-thr rec (chunk rc);
// blocks 1024.. = pk-form 128x64 gemm (chunk rc+1, other cur buffer).
// Launch-boundary dependencies only. Closed-loop math bit-identical. =====
struct RecSh {
    unsigned short slist[2][528];
    unsigned long long zm[8];
    float ypart[4][64];
};
struct GemmSh {
    float As[16][132];   // [k][m], bank (4k+m)%32: 2-way on write, 4-bank bcast on read
    float Bs[16][68];    // [k][n], 2-way on write, 2-way on read
};
union FatSh { RecSh r; GemmSh g; };

__launch_bounds__(256, 8)
__global__ void fat_kernel(const float* __restrict__ cur,
                           const float2* __restrict__ pw,
                           const float* __restrict__ woutT,
                           float* __restrict__ stV, float* __restrict__ stI,
                           float* __restrict__ stVO, float* __restrict__ stIO,
                           unsigned long long* __restrict__ stZM,
                           float* __restrict__ out, int t0, int csteps,
                           const float* __restrict__ gA, const float* __restrict__ gB,
                           float* __restrict__ gC, int G) {
    __shared__ __attribute__((aligned(16))) FatSh sh;

    if (blockIdx.x < 1024) {
        // ---------------- rec role (VERBATIM R8/R11 body) ----------------
        const int b = blockIdx.x;
        const int tid = threadIdx.x;      // 0..255
        const int lane = tid & 63;
        const int w = tid >> 6;           // 0..3
        const int t8 = tid << 3;
        const int l4 = lane << 2;

        const char* __restrict__ pwB   = (const char*)pw;
        const char* __restrict__ woutB = (const char*)woutT;

        float v0 = stV[b * HID + tid];
        float v1 = stV[b * HID + 256 + tid];
        float i0 = stI[b * HID + tid];
        float i1 = stI[b * HID + 256 + tid];
        float vo = 0.f, io = 0.f;
        if (tid < OUT_F) { vo = stVO[b * OUT_F + tid]; io = stIO[b * OUT_F + tid]; }
        if (tid < 8) sh.r.zm[tid] = stZM[b * 8 + tid];
        __syncthreads();

        int cnt, cpad;
        {
            unsigned long long mm[8];
            #pragma unroll
            for (int q = 0; q < 8; ++q) mm[q] = sh.r.zm[q];
            int pc[8], total = 0;
            #pragma unroll
            for (int q = 0; q < 8; ++q) { pc[q] = (int)__popcll(mm[q]); total += pc[q]; }
            unsigned long long lmask = (1ull << lane) - 1ull;
            int pre0 = 0, pre1 = 0;
            #pragma unroll
            for (int q = 0; q < 8; ++q) { if (q < w) pre0 += pc[q]; if (q < w + 4) pre1 += pc[q]; }
            if ((mm[w] >> lane) & 1ull)
                sh.r.slist[0][pre0 + (int)__popcll(mm[w] & lmask)] = (unsigned short)tid;
            if ((mm[w + 4] >> lane) & 1ull)
                sh.r.slist[0][pre1 + (int)__popcll(mm[w + 4] & lmask)] = (unsigned short)(256 + tid);
            cnt = total; cpad = (cnt + 7) & ~7;
            if (tid < 8 && cnt + tid < cpad) sh.r.slist[0][cnt + tid] = (unsigned short)HID;
        }
        __syncthreads();

        const float* __restrict__ curRow = cur + (size_t)b * HID;
        const size_t step_stride = (size_t)BATCH * HID;

        float c0v = curRow[tid];
        float c1v = curRow[256 + tid];
        int cb = 0;
        for (int tl = 0; tl < csteps; ++tl) {
            float c0n = 0.f, c1n = 0.f;
            if (tl + 1 < csteps) {
                curRow += step_stride;
                c0n = curRow[tid];
                c1n = curRow[256 + tid];
            }

            const int kmax = cpad;
            float rec0 = 0.f, rec1 = 0.f;
            for (int k = 0; k < kmax; k += 8) {
                uint4 pk = *(const uint4*)&sh.r.slist[cb][k];
                int o0 = ((pk.x & 0xffff) << 11) | t8;
                int o1 = ((pk.x >> 16) << 11) | t8;
                int o2 = ((pk.y & 0xffff) << 11) | t8;
                int o3 = ((pk.y >> 16) << 11) | t8;
                int o4 = ((pk.z & 0xffff) << 11) | t8;
                int o5 = ((pk.z >> 16) << 11) | t8;
                int o6 = ((pk.w & 0xffff) << 11) | t8;
                int o7 = ((pk.w >> 16) << 11) | t8;
                float2 g0 = *(const float2*)(pwB + o0);
                float2 g1 = *(const float2*)(pwB + o1);
                float2 g2 = *(const float2*)(pwB + o2);
                float2 g3 = *(const float2*)(pwB + o3);
                float2 g4 = *(const float2*)(pwB + o4);
                float2 g5 = *(const float2*)(pwB + o5);
                float2 g6 = *(const float2*)(pwB + o6);
                float2 g7 = *(const float2*)(pwB + o7);
                rec0 += g0.x; rec1 += g0.y;
                rec0 += g1.x; rec1 += g1.y;
                rec0 += g2.x; rec1 += g2.y;
                rec0 += g3.x; rec1 += g3.y;
                rec0 += g4.x; rec1 += g4.y;
                rec0 += g5.x; rec1 += g5.y;
                rec0 += g6.x; rec1 += g6.y;
                rec0 += g7.x; rec1 += g7.y;
            }
            float vd0 = v0 + 0.1f * ((0.0f - v0) + i0);
            float vd1 = v1 + 0.1f * ((0.0f - v1) + i1);
            int s0 = (vd0 > 1.0f) ? 1 : 0;
            int s1 = (vd1 > 1.0f) ? 1 : 0;
            v0 = s0 ? 0.0f : vd0;
            v1 = s1 ? 0.0f : vd1;
            float id0 = i0 + 0.2f * (0.0f - i0);
            float id1 = i1 + 0.2f * (0.0f - i1);
            i0 = (id0 + c0v) + rec0;
            i1 = (id1 + c1v) + rec1;
            c0v = c0n; c1v = c1n;

            unsigned long long m0 = __ballot(s0);
            unsigned long long m1 = __ballot(s1);
            if (lane == 0) { sh.r.zm[w] = m0; sh.r.zm[w + 4] = m1; }
            __syncthreads();
            {
                unsigned long long mq[8];
                #pragma unroll
                for (int q = 0; q < 8; ++q) mq[q] = sh.r.zm[q];
                int pc[8], total = 0;
                #pragma unroll
                for (int q = 0; q < 8; ++q) { pc[q] = (int)__popcll(mq[q]); total += pc[q]; }
                unsigned long long lmask = (1ull << lane) - 1ull;
                int pre0 = 0, pre1 = 0;
                #pragma unroll
                for (int q = 0; q < 8; ++q) { if (q < w) pre0 += pc[q]; if (q < w + 4) pre1 += pc[q]; }
                if ((mq[w] >> lane) & 1ull)
                    sh.r.slist[cb ^ 1][pre0 + (int)__popcll(mq[w] & lmask)] = (unsigned short)tid;
                if ((mq[w + 4] >> lane) & 1ull)
                    sh.r.slist[cb ^ 1][pre1 + (int)__popcll(mq[w + 4] & lmask)] = (unsigned short)(256 + tid);
                cnt = total; cpad = (cnt + 7) & ~7;
                if (tid < 8 && cnt + tid < cpad) sh.r.slist[cb ^ 1][cnt + tid] = (unsigned short)HID;
            }
            __syncthreads();
            {
                float yp = 0.f;
                for (int k = w; k < cnt; k += 4) {
                    int hh = sh.r.slist[cb ^ 1][k];
                    yp += *(const float*)(woutB + ((hh << 8) | l4));
                }
                sh.r.ypart[w][lane] = yp;
            }
            __syncthreads();
            if (tid < OUT_F) {
                float y = ((sh.r.ypart[0][tid] + sh.r.ypart[1][tid]) + sh.r.ypart[2][tid]) + sh.r.ypart[3][tid];
                float von = vo + 0.1f * ((0.0f - vo) + io);
                float iodec = io + 0.2f * (0.0f - io);
                io = iodec + y;
                vo = von;
                out[(((size_t)(t0 + tl)) * BATCH + b) * OUT_F + tid] = von;
            }
            cb ^= 1;
        }
        stV[b * HID + tid] = v0;
        stV[b * HID + 256 + tid] = v1;
        stI[b * HID + tid] = i0;
        stI[b * HID + 256 + tid] = i1;
        if (tid < OUT_F) { stVO[b * OUT_F + tid] = vo; stIO[b * OUT_F + tid] = io; }
        if (tid < 8) stZM[b * 8 + tid] = sh.r.zm[tid];
    } else {
        // ------------- gemm role: pk-form 128x64 tile, BK=16, k-major LDS -------------
        // NUMERICS LOCKED: each C element = one ascending-k fma chain (pk-form
        // proven bit-identical in R9/R10).
        if (G == 0) return;
        const int g = blockIdx.x - 1024;
        const int cpx = G >> 3;
        const int logical = (g & 7) * cpx + (g >> 3);
        const int mb = logical >> 3;        // n-inner: 8 n-tiles share an A panel
        const int nb = logical & 7;

        const int t = threadIdx.x;
        const size_t m0 = (size_t)mb * 128;
        const int n0 = nb * 64;

        // staging: A thread t -> row t>>1 (0..127), k-half (t&1)*8 (8 floats)
        //          B thread t -> row t>>2 (0..63),  k-quarter (t&3)*4 (4 floats)
        const int rA = t >> 1;
        const int kA = (t & 1) << 3;
        const int rB = t >> 2;
        const int kB = (t & 3) << 2;
        const float* Ap = gA + (m0 + (size_t)rA) * IN_F + kA;
        const float* Bp = gB + (size_t)(n0 + rB) * IN_F + kB;

        // microtile: 16x16 thread grid, 8 rows x 4 cols each
        const int tm = t >> 4;
        const int tn = t & 15;

        f32x2 acc[8][2] = {};

        for (int k0 = 0; k0 < IN_F; k0 += 16) {
            float4 a0 = *(const float4*)(Ap + k0);
            float4 a1 = *(const float4*)(Ap + k0 + 4);
            float4 b0 = *(const float4*)(Bp + k0);
            __syncthreads();   // previous iteration's readers done
            {
                float av[8];
                *(float4*)(av + 0) = a0; *(float4*)(av + 4) = a1;
                #pragma unroll
                for (int i = 0; i < 8; ++i) sh.g.As[kA + i][rA] = av[i];
                float bv[4];
                *(float4*)(bv + 0) = b0;
                #pragma unroll
                for (int i = 0; i < 4; ++i) sh.g.Bs[kB + i][rB] = bv[i];
            }
            __syncthreads();
            #pragma unroll
            for (int k = 0; k < 16; ++k) {
                float am[8], bn[4];
                *(float4*)(am + 0) = *(const float4*)&sh.g.As[k][tm * 8];
                *(float4*)(am + 4) = *(const float4*)&sh.g.As[k][tm * 8 + 4];
                *(float4*)(bn + 0) = *(const float4*)&sh.g.Bs[k][tn * 4];
                f32x2 bp0 = { bn[0], bn[1] }, bp1 = { bn[2], bn[3] };
                #pragma unroll
                for (int rr = 0; rr < 8; ++rr) {
                    f32x2 ar = { am[rr], am[rr] };
                    acc[rr][0] = __builtin_elementwise_fma(ar, bp0, acc[rr][0]);
                    acc[rr][1] = __builtin_elementwise_fma(ar, bp1, acc[rr][1]);
                }
            }
        }
        #pragma unroll
        for (int rr = 0; rr < 8; ++rr) {
            float* Cp = gC + (m0 + (size_t)(tm * 8 + rr)) * HID + n0 + tn * 4;
            float4 cv = make_float4(acc[rr][0][0], acc[rr][0][1], acc[rr][1][0], acc[rr][1][1]);
            *(float4*)Cp = cv;
        }
    }
}

extern "C" void kernel_launch(void* const* d_in, const int* in_sizes, int n_in,
                              void* d_out, int out_size, void* d_ws, size_t ws_size,
                              hipStream_t stream) {
    const float* x     = (const float*)d_in[0];
    const float* w_in  = (const float*)d_in[1];
    const float* w_rec = (const float*)d_in[2];
    const float* w_out = (const float*)d_in[3];
    float* out = (float*)d_out;
    char* ws = (char*)d_ws;

    float* stV  = (float*)(ws + OFF_V);
    float* stI  = (float*)(ws + OFF_I);
    float* stVO = (float*)(ws + OFF_VO);
    float* stIO = (float*)(ws + OFF_IO);
    unsigned long long* stZM = (unsigned long long*)(ws + OFF_ZM);
    float2* pw   = (float2*)(ws + OFF_WRT);
    float* woutT = (float*)(ws + OFF_WOT);
    float* curbuf = (float*)(ws + OFF_CUR);

    // chunk size: need TWO ping-pong cur buffers of CHUNK*2MB
    size_t cap = (ws_size > OFF_CUR) ? (ws_size - OFF_CUR) : 0;
    int CHUNK = 64;
    while (CHUNK > 1 && (size_t)2 * CHUNK * BATCH * HID * 4 > cap) CHUNK >>= 1;
    const int NCH = SEQ / CHUNK;
    float* buf0 = curbuf;
    float* buf1 = curbuf + (size_t)CHUNK * BATCH * HID;

    {   // zero persistent state (v, i, vo, io, zmask)
        int n4 = (int)(OFF_WRT / 16);
        int blocks = (n4 + 255) / 256;
        if (blocks > 4096) blocks = 4096;
        hipLaunchKernelGGL(init_state_kernel, dim3(blocks), dim3(256), 0, stream,
                           (float4*)ws, n4);
    }
    hipLaunchKernelGGL(prep_kernel, dim3(512), dim3(256), 0, stream,
                       w_rec, w_out, pw, woutT);

    // prologue: chunk 0 gemm at full occupancy
    hipLaunchKernelGGL(gemm_kernel, dim3(CHUNK * 32), dim3(256), 0, stream,
                       x, w_in, buf0);

    for (int c = 0; c < NCH; ++c) {
        float* rbuf = (c & 1) ? buf1 : buf0;
        float* gbuf = (c & 1) ? buf0 : buf1;
        // 128x64 gemm blocks for chunk c+1: (CHUNK*1024/128) m-tiles x 8 n-tiles
        const int G = (c + 1 < NCH) ? CHUNK * 64 : 0;
        const float* gA = x + (size_t)(c + 1) * CHUNK * BATCH * IN_F;
        hipLaunchKernelGGL(fat_kernel, dim3(1024 + G), dim3(256), 0, stream,
                           rbuf, pw, woutT, stV, stI, stVO, stIO, stZM, out,
                           c * CHUNK, CHUNK, gA, w_in, gbuf, G);
    }
}

// Round 13
// 2677.645 us; speedup vs baseline: 1.4318x; 1.4318x over previous
//
#include <hip/hip_runtime.h>
#include <hip/hip_bf16.h>
#include <stdint.h>

#define SEQ   512
#define BATCH 1024
#define IN_F  256
#define HID   512
#define OUT_F 64

typedef float f32x2 __attribute__((ext_vector_type(2)));

// ws layout (bytes)
static const size_t OFF_V   = 0;          // 1024*512*4 = 2 MB
static const size_t OFF_I   = 2097152;    // 2 MB
static const size_t OFF_VO  = 4194304;    // 256 KB
static const size_t OFF_IO  = 4456448;    // 256 KB
static const size_t OFF_ZM  = 4718592;    // 64 KB
static const size_t OFF_WRT = 4784128;    // pw: 513*256*8 = 1050624 (row 512 zeros)
static const size_t OFF_WOT = 5834752;    // 513*64*4 = 131328 (fp32, row 512 zeros)
static const size_t OFF_CUR = 5966080;    // 2 ping-pong cur buffers, CHUNK*2MB each

__global__ void init_state_kernel(float4* __restrict__ p, int n4) {
    int i = blockIdx.x * blockDim.x + threadIdx.x;
    int stride = gridDim.x * blockDim.x;
    float4 z = make_float4(0.f, 0.f, 0.f, 0.f);
    for (; i < n4; i += stride) p[i] = z;
}

// pw[j][h2] = (w_rec[h2][j], w_rec[h2+256][j]) : one float2 load feeds h2 and h2+256.
__global__ void prep_kernel(const float* __restrict__ wrec, const float* __restrict__ wout,
                            float2* __restrict__ pw, float* __restrict__ woutT) {
    int i = blockIdx.x * blockDim.x + threadIdx.x;
    int stride = gridDim.x * blockDim.x;
    for (int idx = i; idx < 513 * 256; idx += stride) {
        int j = idx >> 8, h2 = idx & 255;
        float2 v = make_float2(0.f, 0.f);
        if (j < 512) {
            v.x = wrec[h2 * 512 + j];
            v.y = wrec[(h2 + 256) * 512 + j];
        }
        pw[idx] = v;
    }
    for (int idx = i; idx < 513 * 64; idx += stride) {
        int h = idx >> 6, o = idx & 63;
        woutT[idx] = (h < 512) ? wout[o * 512 + h] : 0.0f;   // woutT[h][o] = w_out[o][h]
    }
}

// ===== Standalone prologue GEMM (VERBATIM R10; NUMERICS LOCKED: each C[m][n]
// is ONE fma chain over k=0..255 ascending). Full occupancy, 128x128 tile. =====
#define GBM 128
#define GBN 128
#define GBK 16
#define GLDK 132

__launch_bounds__(256)
__global__ void gemm_kernel(const float* __restrict__ A, const float* __restrict__ Bw,
                            float* __restrict__ C) {
    __shared__ float As[2][GBK][GLDK];
    __shared__ float Bs[2][GBK][GLDK];

    const int nwg = gridDim.x;
    const int cpx = nwg >> 3;
    const int logical = ((int)blockIdx.x & 7) * cpx + ((int)blockIdx.x >> 3);
    const int mb = logical >> 2;
    const int nb = logical & 3;

    const int t = threadIdx.x;
    const size_t m0 = (size_t)mb * GBM;
    const int n0 = nb * GBN;

    const int r  = t >> 1;
    const int kh = (t & 1) << 3;
    const float* Ap = A  + (m0 + (size_t)r) * IN_F + kh;
    const float* Bp = Bw + (size_t)(n0 + r) * IN_F + kh;

    const int wv   = t >> 6;
    const int lane = t & 63;
    const int tm = ((wv >> 1) << 3) | (lane >> 3);
    const int tn = ((wv & 1) << 3) | (lane & 7);

    f32x2 acc[8][4] = {};

    {
        float4 a0 = *(const float4*)(Ap + 0);
        float4 a1 = *(const float4*)(Ap + 4);
        float4 b0 = *(const float4*)(Bp + 0);
        float4 b1 = *(const float4*)(Bp + 4);
        float av[8], bv[8];
        *(float4*)(av + 0) = a0; *(float4*)(av + 4) = a1;
        *(float4*)(bv + 0) = b0; *(float4*)(bv + 4) = b1;
        #pragma unroll
        for (int i = 0; i < 8; ++i) {
            As[0][kh + i][r] = av[i];
            Bs[0][kh + i][r] = bv[i];
        }
    }

    int c = 0;
    for (int k0 = 0; k0 < IN_F; k0 += GBK) {
        __syncthreads();
        float4 a0, a1, b0, b1;
        const bool more = (k0 + GBK) < IN_F;
        if (more) {
            const int kn = k0 + GBK;
            a0 = *(const float4*)(Ap + kn);
            a1 = *(const float4*)(Ap + kn + 4);
            b0 = *(const float4*)(Bp + kn);
            b1 = *(const float4*)(Bp + kn + 4);
        }
        #pragma unroll
        for (int k = 0; k < GBK; ++k) {
            float am[8], bn[8];
            *(float4*)(am + 0) = *(const float4*)&As[c][k][tm * 8];
            *(float4*)(am + 4) = *(const float4*)&As[c][k][tm * 8 + 4];
            *(float4*)(bn + 0) = *(const float4*)&Bs[c][k][tn * 8];
            *(float4*)(bn + 4) = *(const float4*)&Bs[c][k][tn * 8 + 4];
            f32x2 bp0 = { bn[0], bn[1] }, bp1 = { bn[2], bn[3] };
            f32x2 bp2 = { bn[4], bn[5] }, bp3 = { bn[6], bn[7] };
            #pragma unroll
            for (int rr = 0; rr < 8; ++rr) {
                f32x2 ar = { am[rr], am[rr] };
                acc[rr][0] = __builtin_elementwise_fma(ar, bp0, acc[rr][0]);
                acc[rr][1] = __builtin_elementwise_fma(ar, bp1, acc[rr][1]);
                acc[rr][2] = __builtin_elementwise_fma(ar, bp2, acc[rr][2]);
                acc[rr][3] = __builtin_elementwise_fma(ar, bp3, acc[rr][3]);
            }
        }
        if (more) {
            float av[8], bv[8];
            *(float4*)(av + 0) = a0; *(float4*)(av + 4) = a1;
            *(float4*)(bv + 0) = b0; *(float4*)(bv + 4) = b1;
            #pragma unroll
            for (int i = 0; i < 8; ++i) {
                As[c ^ 1][kh + i][r] = av[i];
                Bs[c ^ 1][kh + i][r] = bv[i];
            }
        }
        c ^= 1;
    }
    #pragma unroll
    for (int rr = 0; rr < 8; ++rr) {
        float* Cp = C + (m0 + (size_t)(tm * 8 + rr)) * HID + n0 + tn * 8;
        float4 c0 = make_float4(acc[rr][0][0], acc[rr][0][1], acc[rr][1][0], acc[rr][1][1]);
        float4 c1 = make_float4(acc[rr][2][0], acc[rr][2][1], acc[rr][3][0], acc[rr][3][1]);
        *(float4*)(Cp + 0) = c0;
        *(float4*)(Cp + 4) = c1;
    }
}

// ===== FAT kernel: blocks 0..1023 = R8-form 256-thr rec (chunk rc);
// blocks 1024.. = 64x64 gemm role (chunk rc+1, other cur buffer) — R11's
// proven panel size (64 KB A = L3-resident under cur streaming) with the
// bank-conflict fix: k-major LDS [16][68] + pk-fma. Launch-boundary deps
// only. Each C element = one ascending-k fma chain (bit-identical). =====
struct RecSh {
    unsigned short slist[2][528];
    unsigned long long zm[8];
    float ypart[4][64];
};
struct GemmSh {
    float As[16][68];   // [k][m] 64+4 pad: write 2-way, read broadcast
    float Bs[16][68];   // [k][n]: write 2-way, read 2-way — all free
};
union FatSh { RecSh r; GemmSh g; };

__launch_bounds__(256, 8)
__global__ void fat_kernel(const float* __restrict__ cur,
                           const float2* __restrict__ pw,
                           const float* __restrict__ woutT,
                           float* __restrict__ stV, float* __restrict__ stI,
                           float* __restrict__ stVO, float* __restrict__ stIO,
                           unsigned long long* __restrict__ stZM,
                           float* __restrict__ out, int t0, int csteps,
                           const float* __restrict__ gA, const float* __restrict__ gB,
                           float* __restrict__ gC, int G) {
    __shared__ __attribute__((aligned(16))) FatSh sh;

    if (blockIdx.x < 1024) {
        // ---------------- rec role (VERBATIM R8/R11 body) ----------------
        const int b = blockIdx.x;
        const int tid = threadIdx.x;      // 0..255
        const int lane = tid & 63;
        const int w = tid >> 6;           // 0..3
        const int t8 = tid << 3;
        const int l4 = lane << 2;

        const char* __restrict__ pwB   = (const char*)pw;
        const char* __restrict__ woutB = (const char*)woutT;

        float v0 = stV[b * HID + tid];
        float v1 = stV[b * HID + 256 + tid];
        float i0 = stI[b * HID + tid];
        float i1 = stI[b * HID + 256 + tid];
        float vo = 0.f, io = 0.f;
        if (tid < OUT_F) { vo = stVO[b * OUT_F + tid]; io = stIO[b * OUT_F + tid]; }
        if (tid < 8) sh.r.zm[tid] = stZM[b * 8 + tid];
        __syncthreads();

        int cnt, cpad;
        {
            unsigned long long mm[8];
            #pragma unroll
            for (int q = 0; q < 8; ++q) mm[q] = sh.r.zm[q];
            int pc[8], total = 0;
            #pragma unroll
            for (int q = 0; q < 8; ++q) { pc[q] = (int)__popcll(mm[q]); total += pc[q]; }
            unsigned long long lmask = (1ull << lane) - 1ull;
            int pre0 = 0, pre1 = 0;
            #pragma unroll
            for (int q = 0; q < 8; ++q) { if (q < w) pre0 += pc[q]; if (q < w + 4) pre1 += pc[q]; }
            if ((mm[w] >> lane) & 1ull)
                sh.r.slist[0][pre0 + (int)__popcll(mm[w] & lmask)] = (unsigned short)tid;
            if ((mm[w + 4] >> lane) & 1ull)
                sh.r.slist[0][pre1 + (int)__popcll(mm[w + 4] & lmask)] = (unsigned short)(256 + tid);
            cnt = total; cpad = (cnt + 7) & ~7;
            if (tid < 8 && cnt + tid < cpad) sh.r.slist[0][cnt + tid] = (unsigned short)HID;
        }
        __syncthreads();

        const float* __restrict__ curRow = cur + (size_t)b * HID;
        const size_t step_stride = (size_t)BATCH * HID;

        float c0v = curRow[tid];
        float c1v = curRow[256 + tid];
        int cb = 0;
        for (int tl = 0; tl < csteps; ++tl) {
            float c0n = 0.f, c1n = 0.f;
            if (tl + 1 < csteps) {
                curRow += step_stride;
                c0n = curRow[tid];
                c1n = curRow[256 + tid];
            }

            const int kmax = cpad;
            float rec0 = 0.f, rec1 = 0.f;
            for (int k = 0; k < kmax; k += 8) {
                uint4 pk = *(const uint4*)&sh.r.slist[cb][k];
                int o0 = ((pk.x & 0xffff) << 11) | t8;
                int o1 = ((pk.x >> 16) << 11) | t8;
                int o2 = ((pk.y & 0xffff) << 11) | t8;
                int o3 = ((pk.y >> 16) << 11) | t8;
                int o4 = ((pk.z & 0xffff) << 11) | t8;
                int o5 = ((pk.z >> 16) << 11) | t8;
                int o6 = ((pk.w & 0xffff) << 11) | t8;
                int o7 = ((pk.w >> 16) << 11) | t8;
                float2 g0 = *(const float2*)(pwB + o0);
                float2 g1 = *(const float2*)(pwB + o1);
                float2 g2 = *(const float2*)(pwB + o2);
                float2 g3 = *(const float2*)(pwB + o3);
                float2 g4 = *(const float2*)(pwB + o4);
                float2 g5 = *(const float2*)(pwB + o5);
                float2 g6 = *(const float2*)(pwB + o6);
                float2 g7 = *(const float2*)(pwB + o7);
                rec0 += g0.x; rec1 += g0.y;
                rec0 += g1.x; rec1 += g1.y;
                rec0 += g2.x; rec1 += g2.y;
                rec0 += g3.x; rec1 += g3.y;
                rec0 += g4.x; rec1 += g4.y;
                rec0 += g5.x; rec1 += g5.y;
                rec0 += g6.x; rec1 += g6.y;
                rec0 += g7.x; rec1 += g7.y;
            }
            float vd0 = v0 + 0.1f * ((0.0f - v0) + i0);
            float vd1 = v1 + 0.1f * ((0.0f - v1) + i1);
            int s0 = (vd0 > 1.0f) ? 1 : 0;
            int s1 = (vd1 > 1.0f) ? 1 : 0;
            v0 = s0 ? 0.0f : vd0;
            v1 = s1 ? 0.0f : vd1;
            float id0 = i0 + 0.2f * (0.0f - i0);
            float id1 = i1 + 0.2f * (0.0f - i1);
            i0 = (id0 + c0v) + rec0;
            i1 = (id1 + c1v) + rec1;
            c0v = c0n; c1v = c1n;

            unsigned long long m0 = __ballot(s0);
            unsigned long long m1 = __ballot(s1);
            if (lane == 0) { sh.r.zm[w] = m0; sh.r.zm[w + 4] = m1; }
            __syncthreads();
            {
                unsigned long long mq[8];
                #pragma unroll
                for (int q = 0; q < 8; ++q) mq[q] = sh.r.zm[q];
                int pc[8], total = 0;
                #pragma unroll
                for (int q = 0; q < 8; ++q) { pc[q] = (int)__popcll(mq[q]); total += pc[q]; }
                unsigned long long lmask = (1ull << lane) - 1ull;
                int pre0 = 0, pre1 = 0;
                #pragma unroll
                for (int q = 0; q < 8; ++q) { if (q < w) pre0 += pc[q]; if (q < w + 4) pre1 += pc[q]; }
                if ((mq[w] >> lane) & 1ull)
                    sh.r.slist[cb ^ 1][pre0 + (int)__popcll(mq[w] & lmask)] = (unsigned short)tid;
                if ((mq[w + 4] >> lane) & 1ull)
                    sh.r.slist[cb ^ 1][pre1 + (int)__popcll(mq[w + 4] & lmask)] = (unsigned short)(256 + tid);
                cnt = total; cpad = (cnt + 7) & ~7;
                if (tid < 8 && cnt + tid < cpad) sh.r.slist[cb ^ 1][cnt + tid] = (unsigned short)HID;
            }
            __syncthreads();
            {
                float yp = 0.f;
                for (int k = w; k < cnt; k += 4) {
                    int hh = sh.r.slist[cb ^ 1][k];
                    yp += *(const float*)(woutB + ((hh << 8) | l4));
                }
                sh.r.ypart[w][lane] = yp;
            }
            __syncthreads();
            if (tid < OUT_F) {
                float y = ((sh.r.ypart[0][tid] + sh.r.ypart[1][tid]) + sh.r.ypart[2][tid]) + sh.r.ypart[3][tid];
                float von = vo + 0.1f * ((0.0f - vo) + io);
                float iodec = io + 0.2f * (0.0f - io);
                io = iodec + y;
                vo = von;
                out[(((size_t)(t0 + tl)) * BATCH + b) * OUT_F + tid] = von;
            }
            cb ^= 1;
        }
        stV[b * HID + tid] = v0;
        stV[b * HID + 256 + tid] = v1;
        stI[b * HID + tid] = i0;
        stI[b * HID + 256 + tid] = i1;
        if (tid < OUT_F) { stVO[b * OUT_F + tid] = vo; stIO[b * OUT_F + tid] = io; }
        if (tid < 8) stZM[b * 8 + tid] = sh.r.zm[tid];
    } else {
        // ---- gemm role: 64x64 tile (L3-friendly 64 KB A panel), k-major LDS, pk-fma ----
        if (G == 0) return;
        const int g = blockIdx.x - 1024;
        const int cpx = G >> 3;
        const int logical = (g & 7) * cpx + (g >> 3);
        const int mb = logical >> 3;        // n-inner: 8 n-tiles share an A panel
        const int nb = logical & 7;

        const int t = threadIdx.x;
        const size_t m0 = (size_t)mb * 64;
        const int n0 = nb * 64;

        // staging: thread t -> row t>>2 (0..63), k-quarter (t&3)*4 (4 floats)
        const int r  = t >> 2;
        const int kq = (t & 3) << 2;
        const float* Ap = gA + (m0 + (size_t)r) * IN_F + kq;
        const float* Bp = gB + (size_t)(n0 + r) * IN_F + kq;

        // microtile: 16x16 thread grid, 4x4 each
        const int tm = t >> 4;
        const int tn = t & 15;

        f32x2 acc[4][2] = {};

        for (int k0 = 0; k0 < IN_F; k0 += 16) {
            float4 a4 = *(const float4*)(Ap + k0);
            float4 b4 = *(const float4*)(Bp + k0);
            __syncthreads();   // previous iteration's readers done
            {
                float av[4], bv[4];
                *(float4*)av = a4;
                *(float4*)bv = b4;
                #pragma unroll
                for (int i = 0; i < 4; ++i) {
                    sh.g.As[kq + i][r] = av[i];   // bank (4(kq+i)+r)%32: 2-way, free
                    sh.g.Bs[kq + i][r] = bv[i];
                }
            }
            __syncthreads();
            #pragma unroll
            for (int k = 0; k < 16; ++k) {
                float am[4], bn[4];
                *(float4*)am = *(const float4*)&sh.g.As[k][tm * 4];   // broadcast read
                *(float4*)bn = *(const float4*)&sh.g.Bs[k][tn * 4];   // 2-way read
                f32x2 bp0 = { bn[0], bn[1] }, bp1 = { bn[2], bn[3] };
                #pragma unroll
                for (int rr = 0; rr < 4; ++rr) {
                    f32x2 ar = { am[rr], am[rr] };
                    acc[rr][0] = __builtin_elementwise_fma(ar, bp0, acc[rr][0]);
                    acc[rr][1] = __builtin_elementwise_fma(ar, bp1, acc[rr][1]);
                }
            }
        }
        #pragma unroll
        for (int rr = 0; rr < 4; ++rr) {
            float* Cp = gC + (m0 + (size_t)(tm * 4 + rr)) * HID + n0 + tn * 4;
            float4 cv = make_float4(acc[rr][0][0], acc[rr][0][1], acc[rr][1][0], acc[rr][1][1]);
            *(float4*)Cp = cv;
        }
    }
}

extern "C" void kernel_launch(void* const* d_in, const int* in_sizes, int n_in,
                              void* d_out, int out_size, void* d_ws, size_t ws_size,
                              hipStream_t stream) {
    const float* x     = (const float*)d_in[0];
    const float* w_in  = (const float*)d_in[1];
    const float* w_rec = (const float*)d_in[2];
    const float* w_out = (const float*)d_in[3];
    float* out = (float*)d_out;
    char* ws = (char*)d_ws;

    float* stV  = (float*)(ws + OFF_V);
    float* stI  = (float*)(ws + OFF_I);
    float* stVO = (float*)(ws + OFF_VO);
    float* stIO = (float*)(ws + OFF_IO);
    unsigned long long* stZM = (unsigned long long*)(ws + OFF_ZM);
    float2* pw   = (float2*)(ws + OFF_WRT);
    float* woutT = (float*)(ws + OFF_WOT);
    float* curbuf = (float*)(ws + OFF_CUR);

    // chunk size: need TWO ping-pong cur buffers of CHUNK*2MB
    size_t cap = (ws_size > OFF_CUR) ? (ws_size - OFF_CUR) : 0;
    int CHUNK = 64;
    while (CHUNK > 1 && (size_t)2 * CHUNK * BATCH * HID * 4 > cap) CHUNK >>= 1;
    const int NCH = SEQ / CHUNK;
    float* buf0 = curbuf;
    float* buf1 = curbuf + (size_t)CHUNK * BATCH * HID;

    {   // zero persistent state (v, i, vo, io, zmask)
        int n4 = (int)(OFF_WRT / 16);
        int blocks = (n4 + 255) / 256;
        if (blocks > 4096) blocks = 4096;
        hipLaunchKernelGGL(init_state_kernel, dim3(blocks), dim3(256), 0, stream,
                           (float4*)ws, n4);
    }
    hipLaunchKernelGGL(prep_kernel, dim3(512), dim3(256), 0, stream,
                       w_rec, w_out, pw, woutT);

    // prologue: chunk 0 gemm at full occupancy
    hipLaunchKernelGGL(gemm_kernel, dim3(CHUNK * 32), dim3(256), 0, stream,
                       x, w_in, buf0);

    for (int c = 0; c < NCH; ++c) {
        float* rbuf = (c & 1) ? buf1 : buf0;
        float* gbuf = (c & 1) ? buf0 : buf1;
        const int G = (c + 1 < NCH) ? CHUNK * 128 : 0;   // 64x64 blocks for chunk c+1
        const float* gA = x + (size_t)(c + 1) * CHUNK * BATCH * IN_F;
        hipLaunchKernelGGL(fat_kernel, dim3(1024 + G), dim3(256), 0, stream,
                           rbuf, pw, woutT, stV, stI, stVO, stIO, stZM, out,
                           c * CHUNK, CHUNK, gA, w_in, gbuf, G);
    }
}